// Round 6
// baseline (699.094 us; speedup 1.0000x reference)
//
#include <hip/hip_runtime.h>
#include <math.h>

#define F 128
#define HEADS 8

typedef __attribute__((ext_vector_type(8))) short short8;
typedef __attribute__((ext_vector_type(4))) float floatx4;
typedef __attribute__((ext_vector_type(2))) _Float16 half2v;

__device__ __forceinline__ unsigned short f2bf(float f) {
    unsigned u = __float_as_uint(f);
    unsigned r = u + 0x7FFFu + ((u >> 16) & 1u);
    return (unsigned short)(r >> 16);
}

__device__ __forceinline__ half2v ashalf2(unsigned u) {
    return __builtin_bit_cast(half2v, u);
}
__device__ __forceinline__ unsigned pkh(float a, float b) {
    return __builtin_bit_cast(unsigned, __builtin_amdgcn_cvt_pkrtz(a, b));
}

#if __has_builtin(__builtin_amdgcn_fdot2)
#define FDOT2(a, b, c) __builtin_amdgcn_fdot2((a), (b), (c), false)
#else
#define FDOT2(a, b, c) ((c) + (float)(a)[0] * (float)(b)[0] + (float)(a)[1] * (float)(b)[1])
#endif

// ---------------- fused setup: x->bf16 cvt + weight pre-swizzle + zero deg/cursor ----------------

__global__ __launch_bounds__(256) void setup_k(
    const float* __restrict__ x, unsigned short* __restrict__ xb, int total4,
    const float* __restrict__ Wq, const float* __restrict__ Wk,
    const float* __restrict__ Wv, const float* __restrict__ Ws,
    unsigned short* __restrict__ wfrag, int wtotal,
    int* __restrict__ deg, int* __restrict__ cursor, int N) {
    int idx = blockIdx.x * 256 + threadIdx.x;
    if (idx < total4) {
        float4 v = ((const float4*)x)[idx];
        ushort4 o;
        o.x = f2bf(v.x); o.y = f2bf(v.y); o.z = f2bf(v.z); o.w = f2bf(v.w);
        ((ushort4*)xb)[idx] = o;
        return;
    }
    idx -= total4;
    if (idx < wtotal) {
        int j = idx & 7;
        int lane = (idx >> 3) & 63;
        int rest = idx >> 9;
        int chunk = rest & 3;
        int ftile = (rest >> 2) & 7;
        int mat = (rest >> 5) & 3;
        int layer = rest >> 7;
        int k = chunk * 32 + (lane >> 4) * 8 + j;
        int f = ftile * 16 + (lane & 15);
        const float* W = (mat == 0) ? Wq : (mat == 1) ? Wk : (mat == 2) ? Wv : Ws;
        wfrag[idx] = f2bf(W[((size_t)layer * F + k) * F + f]);
        return;
    }
    idx -= wtotal;
    if (idx < N) deg[idx] = 0;
    else if (idx < 2 * N) cursor[idx - N] = 0;
}

// ---------------- CSR build ----------------

__global__ __launch_bounds__(256) void hist_k(const int* __restrict__ dst, int E, int* __restrict__ deg) {
    int e = blockIdx.x * 256 + threadIdx.x;
    if (e < E) atomicAdd(&deg[dst[e]], 1);
}

__global__ __launch_bounds__(256) void scan1_k(const int* __restrict__ deg, int N,
                                               int* __restrict__ start, int* __restrict__ partials) {
    __shared__ int sm[256];
    int t = threadIdx.x;
    int i = blockIdx.x * 256 + t;
    int v = (i < N) ? deg[i] : 0;
    sm[t] = v;
    __syncthreads();
    for (int off = 1; off < 256; off <<= 1) {
        int add = (t >= off) ? sm[t - off] : 0;
        __syncthreads();
        sm[t] += add;
        __syncthreads();
    }
    if (i < N) start[i] = sm[t] - v;
    if (t == 255) partials[blockIdx.x] = sm[t];
}

__global__ __launch_bounds__(256) void scan23_k(const int* __restrict__ partials, int nb,
                                                int* __restrict__ start, int N, int E) {
    __shared__ int sm[256];
    int t = threadIdx.x;
    int v = (t < nb) ? partials[t] : 0;
    sm[t] = v;
    __syncthreads();
    for (int off = 1; off < 256; off <<= 1) {
        int add = (t >= off) ? sm[t - off] : 0;
        __syncthreads();
        sm[t] += add;
        __syncthreads();
    }
    int myoff = sm[t] - v;
    __syncthreads();
    sm[t] = myoff;
    __syncthreads();
    for (int i = t; i < N; i += 256) start[i] += sm[i >> 8];
    if (t == 0) start[N] = E;
}

// epair[i] = (edge_id, src)
__global__ __launch_bounds__(256) void fill_k(const int* __restrict__ src, const int* __restrict__ dst, int E,
                                              const int* __restrict__ start, int* __restrict__ cursor,
                                              int2* __restrict__ epair) {
    int e = blockIdx.x * 256 + threadIdx.x;
    if (e < E) {
        int dd = dst[e];
        int pos = atomicAdd(&cursor[dd], 1);
        epair[start[dd] + pos] = make_int2(e, src[e]);
    }
}

// ---------------- fused QKVS GEMM via bf16 MFMA ----------------
// wave 0:Q 1:K 2:V 3:S, all f16 outputs, 32 nodes per block.

__global__ __launch_bounds__(256) void gemm_mfma(
    const unsigned short* __restrict__ xb, const unsigned short* __restrict__ wfrag,
    const float* __restrict__ bq, const float* __restrict__ bk,
    const float* __restrict__ bv, const float* __restrict__ bs,
    unsigned short* __restrict__ Qh, unsigned short* __restrict__ Kh,
    unsigned short* __restrict__ Vh, unsigned short* __restrict__ Sh, int N) {
    int wave = threadIdx.x >> 6;
    int lane = threadIdx.x & 63;
    int row0 = blockIdx.x * 32;
    int lm = lane & 15, quad = lane >> 4;
    const unsigned short* wf = wfrag + wave * 16384;

    floatx4 acc[2][8];
#pragma unroll
    for (int t = 0; t < 2; t++)
#pragma unroll
        for (int u = 0; u < 8; u++) acc[t][u] = (floatx4){0.f, 0.f, 0.f, 0.f};

#pragma unroll
    for (int chunk = 0; chunk < 4; chunk++) {
        short8 xfr[2];
#pragma unroll
        for (int t = 0; t < 2; t++) {
            int m = row0 + t * 16 + lm;
            m = (m < N) ? m : (N - 1);
            xfr[t] = *(const short8*)(xb + (size_t)m * F + chunk * 32 + quad * 8);
        }
#pragma unroll
        for (int u = 0; u < 8; u++) {
            short8 wfr = *(const short8*)(wf + ((u * 4 + chunk) * 64 + lane) * 8);
            acc[0][u] = __builtin_amdgcn_mfma_f32_16x16x32_bf16(wfr, xfr[0], acc[0][u], 0, 0, 0);
            acc[1][u] = __builtin_amdgcn_mfma_f32_16x16x32_bf16(wfr, xfr[1], acc[1][u], 0, 0, 0);
        }
    }

    const float* bias = (wave == 0) ? bq : (wave == 1) ? bk : (wave == 2) ? bv : bs;
    unsigned short* dp = (wave == 0) ? Qh : (wave == 1) ? Kh : (wave == 2) ? Vh : Sh;
#pragma unroll
    for (int u = 0; u < 8; u++) {
        float4 bv4 = *(const float4*)&bias[u * 16 + quad * 4];
#pragma unroll
        for (int t = 0; t < 2; t++) {
            int node = row0 + t * 16 + lm;
            if (node < N) {
                floatx4 a = acc[t][u];
                size_t off = (size_t)node * F + u * 16 + quad * 4;
                *(uint2*)&dp[off] = make_uint2(pkh(a[0] + bv4.x, a[1] + bv4.y),
                                               pkh(a[2] + bv4.z, a[3] + bv4.w));
            }
        }
    }
}

// ---------------- fused edge kernel: persistent, one wave per destination node ----------------
// Grid = 2048 blocks (8/CU), each wave strides over nodes: pins occupancy at
// the 32-wave/CU cap, removes launch ramp/tail.
// Phase 1 unrolled x2: two independent K-gather->dot->exp chains in flight.
// Phase 2: V rows f16 16B/lane. Epilogue spread over all 64 lanes.

__device__ __forceinline__ float gelu_exact(float v) {
    return 0.5f * v * (1.0f + erff(v * 0.70710678118654752f));
}

__global__ __launch_bounds__(256) void edge_k(
    const unsigned short* __restrict__ Qh, const unsigned short* __restrict__ Kh,
    const unsigned short* __restrict__ Vh, const unsigned short* __restrict__ Sh,
    const int* __restrict__ start, const int2* __restrict__ epair,
    float* __restrict__ aout,
    float* __restrict__ hout_f, unsigned short* __restrict__ hout_b,
    int N, int do_gelu) {
    __shared__ float wbuf[4][64][8];   // w values; reused for output partials
    __shared__ int sbuf[4][64];        // src byte offsets (src * 256)
    __shared__ int ebuf[4][64];        // edge ids
    __shared__ float mdbuf[4][8];

    int wv = threadIdx.x >> 6;
    int lane = threadIdx.x & 63;
    int slot = lane >> 3, h = lane & 7;
    int g = lane >> 4, fl = lane & 15;
    int fh = fl >> 1;
    int stride = gridDim.x * 4;

    for (int n = blockIdx.x * 4 + wv; n < N; n += stride) {

        int beg = start[n], end = start[n + 1];
        int deg = end - beg;
        bool multi = deg > 64;

        // q for head h: 16 f16
        const unsigned short* qp = Qh + (size_t)n * F + h * 16;
        uint4 qa = *(const uint4*)(qp);
        uint4 qc = *(const uint4*)(qp + 8);
        half2v q0 = ashalf2(qa.x), q1 = ashalf2(qa.y), q2 = ashalf2(qa.z), q3 = ashalf2(qa.w);
        half2v q4 = ashalf2(qc.x), q5 = ashalf2(qc.y), q6 = ashalf2(qc.z), q7 = ashalf2(qc.w);

        float d = 0.f;
        float a0 = 0.f, a1 = 0.f, a2 = 0.f, a3 = 0.f, a4 = 0.f, a5 = 0.f, a6 = 0.f, a7 = 0.f;

        for (int c0 = beg; c0 < end; c0 += 64) {
            int cnt = min(64, end - c0);

            // one coalesced load covers the chunk; distribute through LDS
            int2 pe = epair[c0 + min(lane, cnt - 1)];
            sbuf[wv][lane] = pe.y << 8;     // src * F * sizeof(f16)
            ebuf[wv][lane] = pe.x;

            // ---- phase 1: alpha / w, unrolled x2 (independent chains) ----
            int nit = (cnt + 7) >> 3;
            int it = 0;
            for (; it + 2 <= nit; it += 2) {
                int idxA = it * 8 + slot;          // always < cnt
                int idxB = idxA + 8;
                bool valB = idxB < cnt;
                int ofsA = sbuf[wv][idxA];
                int ofsB = sbuf[wv][valB ? idxB : 0];
                const unsigned short* kpA = (const unsigned short*)((const char*)Kh + ofsA) + h * 16;
                const unsigned short* kpB = (const unsigned short*)((const char*)Kh + ofsB) + h * 16;
                uint4 kaA = *(const uint4*)(kpA);
                uint4 kcA = *(const uint4*)(kpA + 8);
                uint4 kaB = *(const uint4*)(kpB);
                uint4 kcB = *(const uint4*)(kpB + 8);
                float pA0 = 0.f, pA1 = 0.f, pB0 = 0.f, pB1 = 0.f;
                pA0 = FDOT2(q0, ashalf2(kaA.x), pA0);
                pA0 = FDOT2(q1, ashalf2(kaA.y), pA0);
                pA0 = FDOT2(q2, ashalf2(kaA.z), pA0);
                pA0 = FDOT2(q3, ashalf2(kaA.w), pA0);
                pA1 = FDOT2(q4, ashalf2(kcA.x), pA1);
                pA1 = FDOT2(q5, ashalf2(kcA.y), pA1);
                pA1 = FDOT2(q6, ashalf2(kcA.z), pA1);
                pA1 = FDOT2(q7, ashalf2(kcA.w), pA1);
                pB0 = FDOT2(q0, ashalf2(kaB.x), pB0);
                pB0 = FDOT2(q1, ashalf2(kaB.y), pB0);
                pB0 = FDOT2(q2, ashalf2(kaB.z), pB0);
                pB0 = FDOT2(q3, ashalf2(kaB.w), pB0);
                pB1 = FDOT2(q4, ashalf2(kcB.x), pB1);
                pB1 = FDOT2(q5, ashalf2(kcB.y), pB1);
                pB1 = FDOT2(q6, ashalf2(kcB.z), pB1);
                pB1 = FDOT2(q7, ashalf2(kcB.w), pB1);
                float wA = __expf((pA0 + pA1) * 0.25f);
                float wB = __expf((pB0 + pB1) * 0.25f);
                if (!valB) wB = 0.f;
                d += wA + wB;
                wbuf[wv][idxA][h] = wA;
                wbuf[wv][idxB][h] = wB;
                if (multi) {
                    aout[(size_t)ebuf[wv][idxA] * HEADS + h] = wA;
                    if (valB) aout[(size_t)ebuf[wv][idxB] * HEADS + h] = wB;
                }
            }
            for (; it < nit; it++) {
                int idx = it * 8 + slot;
                bool val = idx < cnt;
                int ofs = sbuf[wv][val ? idx : 0];
                const unsigned short* kp = (const unsigned short*)((const char*)Kh + ofs) + h * 16;
                uint4 ka = *(const uint4*)(kp);
                uint4 kc = *(const uint4*)(kp + 8);
                float p0 = 0.f, p1 = 0.f;
                p0 = FDOT2(q0, ashalf2(ka.x), p0);
                p0 = FDOT2(q1, ashalf2(ka.y), p0);
                p0 = FDOT2(q2, ashalf2(ka.z), p0);
                p0 = FDOT2(q3, ashalf2(ka.w), p0);
                p1 = FDOT2(q4, ashalf2(kc.x), p1);
                p1 = FDOT2(q5, ashalf2(kc.y), p1);
                p1 = FDOT2(q6, ashalf2(kc.z), p1);
                p1 = FDOT2(q7, ashalf2(kc.w), p1);
                float w = __expf((p0 + p1) * 0.25f);
                if (!val) w = 0.f;
                d += w;
                wbuf[wv][idx][h] = w;
                if (multi && val) aout[(size_t)ebuf[wv][idx] * HEADS + h] = w;
            }

            // ---- phase 2: V accumulation ----
            for (int j = 0; j < cnt; j += 8) {
                int idx0 = j + g;
                int idx1 = j + 4 + g;
                bool v0 = idx0 < cnt;
                bool v1 = idx1 < cnt;
                int o0s = sbuf[wv][v0 ? idx0 : 0];
                int o1s = sbuf[wv][v1 ? idx1 : 0];
                float w0 = wbuf[wv][v0 ? idx0 : 0][fh];
                float w1 = wbuf[wv][v1 ? idx1 : 0][fh];
                if (!v0) w0 = 0.f;
                if (!v1) w1 = 0.f;
                uint4 va = *(const uint4*)((const char*)Vh + o0s + fl * 16);
                uint4 vb2 = *(const uint4*)((const char*)Vh + o1s + fl * 16);
                half2v x0 = ashalf2(va.x), x1 = ashalf2(va.y), x2 = ashalf2(va.z), x3 = ashalf2(va.w);
                half2v y0 = ashalf2(vb2.x), y1 = ashalf2(vb2.y), y2 = ashalf2(vb2.z), y3 = ashalf2(vb2.w);
                a0 += w0 * (float)x0[0]; a1 += w0 * (float)x0[1];
                a2 += w0 * (float)x1[0]; a3 += w0 * (float)x1[1];
                a4 += w0 * (float)x2[0]; a5 += w0 * (float)x2[1];
                a6 += w0 * (float)x3[0]; a7 += w0 * (float)x3[1];
                a0 += w1 * (float)y0[0]; a1 += w1 * (float)y0[1];
                a2 += w1 * (float)y1[0]; a3 += w1 * (float)y1[1];
                a4 += w1 * (float)y2[0]; a5 += w1 * (float)y2[1];
                a6 += w1 * (float)y3[0]; a7 += w1 * (float)y3[1];
            }
        }

        // reduce d over slots (lanes sharing h)
        d += __shfl_xor(d, 8);
        d += __shfl_xor(d, 16);
        d += __shfl_xor(d, 32);
        float inv_d = (d > 0.f) ? 1.f / d : 0.f;
        if (slot == 0) mdbuf[wv][h] = inv_d;

        // ---- fused alpha normalization (last=only chunk still in LDS) ----
        if (!multi) {
            for (int idx = slot; idx < deg; idx += 8)
                aout[(size_t)ebuf[wv][idx] * HEADS + h] = wbuf[wv][idx][h] * inv_d;
        } else {
            for (int idx = slot; idx < deg; idx += 8)
                aout[(size_t)epair[beg + idx].x * HEADS + h] *= inv_d;
        }

        // ---- epilogue spread over all 64 lanes ----
        *(float4*)&wbuf[wv][lane][0] = make_float4(a0, a1, a2, a3);
        *(float4*)&wbuf[wv][lane][4] = make_float4(a4, a5, a6, a7);
        asm volatile("s_waitcnt lgkmcnt(0)" ::: "memory");

        int f0 = lane * 2;
        int frow = f0 >> 3;
        int fcol = f0 & 7;
        float t0 = 0.f, t1 = 0.f;
#pragma unroll
        for (int gg = 0; gg < 4; gg++) {
            float2 pr = *(const float2*)&wbuf[wv][gg * 16 + frow][fcol];
            t0 += pr.x; t1 += pr.y;
        }
        float invd = mdbuf[wv][lane >> 3];
        half2v s2 = ashalf2(*(const unsigned*)&Sh[(size_t)n * F + f0]);
        float o0 = t0 * invd + (float)s2[0];
        float o1 = t1 * invd + (float)s2[1];
        if (do_gelu) {
            o0 = gelu_exact(o0);
            o1 = gelu_exact(o1);
            unsigned ob = (unsigned)f2bf(o0) | ((unsigned)f2bf(o1) << 16);
            *(unsigned*)&hout_b[(size_t)n * F + f0] = ob;
        } else {
            *(float2*)&hout_f[(size_t)n * F + f0] = make_float2(o0, o1);
        }
    }
}

// ---------------- launch ----------------

extern "C" void kernel_launch(void* const* d_in, const int* in_sizes, int n_in,
                              void* d_out, int out_size, void* d_ws, size_t ws_size,
                              hipStream_t stream) {
    const float* x  = (const float*)d_in[0];
    const int*   ei = (const int*)d_in[1];
    const float* Wq = (const float*)d_in[2];
    const float* bq = (const float*)d_in[3];
    const float* Wk = (const float*)d_in[4];
    const float* bk = (const float*)d_in[5];
    const float* Wv = (const float*)d_in[6];
    const float* bv = (const float*)d_in[7];
    const float* Ws = (const float*)d_in[8];
    const float* bs = (const float*)d_in[9];

    const int N = in_sizes[0] / F;
    const int E = in_sizes[1] / 2;
    const int L = in_sizes[2] / (F * F);

    // workspace layout (all f16 node tensors)
    unsigned short* Sh = (unsigned short*)d_ws;           // N*F f16
    unsigned short* Qh = Sh + (size_t)N * F;              // N*F f16
    unsigned short* xb = Qh + (size_t)N * F;              // N*F bf16
    unsigned short* hb = xb + (size_t)N * F;              // N*F bf16
    unsigned short* Kb = hb + (size_t)N * F;              // N*F f16
    unsigned short* Vb = Kb + (size_t)N * F;              // N*F f16
    unsigned short* wfrag = Vb + (size_t)N * F;           // L*4*16384 bf16
    int2* epair = (int2*)(wfrag + (size_t)L * 4 * 16384); // E int2
    int* start = (int*)(epair + E);                       // N+1
    int* cursor = start + (N + 1);                        // N
    int* deg = cursor + N;                                // N
    int* partials = deg + N;                              // <=256

    float* out_h = (float*)d_out;                         // N*F
    float* out_a = out_h + (size_t)N * F;                 // L*E*HEADS

    const int* srcIdx = ei;
    const int* dstIdx = ei + E;

    int total4 = N * F / 4;
    int wtotal = L * 4 * 16384;
    int stotal = total4 + wtotal + 2 * N;
    setup_k<<<(stotal + 255) / 256, 256, 0, stream>>>(
        x, xb, total4, Wq, Wk, Wv, Ws, wfrag, wtotal, deg, cursor, N);

    int nbScan = (N + 255) / 256;
    hist_k<<<(E + 255) / 256, 256, 0, stream>>>(dstIdx, E, deg);
    scan1_k<<<nbScan, 256, 0, stream>>>(deg, N, start, partials);
    scan23_k<<<1, 256, 0, stream>>>(partials, nbScan, start, N, E);
    fill_k<<<(E + 255) / 256, 256, 0, stream>>>(srcIdx, dstIdx, E, start, cursor, epair);

    int egrid = (N + 3) / 4;
    if (egrid > 2048) egrid = 2048;   // 8 blocks/CU, persistent grid-stride

    for (int l = 0; l < L; ++l) {
        const unsigned short* hin = (l == 0) ? xb : hb;
        gemm_mfma<<<(N + 31) / 32, 256, 0, stream>>>(
            hin, wfrag + (size_t)l * 4 * 16384,
            bq + (size_t)l * F, bk + (size_t)l * F,
            bv + (size_t)l * F, bs + (size_t)l * F,
            Qh, Kb, Vb, Sh, N);
        edge_k<<<egrid, 256, 0, stream>>>(
            Qh, Kb, Vb, Sh, start, epair,
            out_a + (size_t)l * E * HEADS, out_h, hb, N, (l < L - 1) ? 1 : 0);
    }
}

// Round 7
// 673.469 us; speedup vs baseline: 1.0380x; 1.0380x over previous
//
#include <hip/hip_runtime.h>
#include <math.h>

#define F 128
#define HEADS 8

typedef __attribute__((ext_vector_type(8))) short short8;
typedef __attribute__((ext_vector_type(4))) float floatx4;
typedef __attribute__((ext_vector_type(2))) _Float16 half2v;

__device__ __forceinline__ unsigned short f2bf(float f) {
    unsigned u = __float_as_uint(f);
    unsigned r = u + 0x7FFFu + ((u >> 16) & 1u);
    return (unsigned short)(r >> 16);
}

__device__ __forceinline__ half2v ashalf2(unsigned u) {
    return __builtin_bit_cast(half2v, u);
}
__device__ __forceinline__ unsigned pkh(float a, float b) {
    return __builtin_bit_cast(unsigned, __builtin_amdgcn_cvt_pkrtz(a, b));
}

#if __has_builtin(__builtin_amdgcn_fdot2)
#define FDOT2(a, b, c) __builtin_amdgcn_fdot2((a), (b), (c), false)
#else
#define FDOT2(a, b, c) ((c) + (float)(a)[0] * (float)(b)[0] + (float)(a)[1] * (float)(b)[1])
#endif

// ---------------- fused setup: x->bf16 cvt + weight pre-swizzle + zero deg/cursor ----------------

__global__ __launch_bounds__(256) void setup_k(
    const float* __restrict__ x, unsigned short* __restrict__ xb, int total4,
    const float* __restrict__ Wq, const float* __restrict__ Wk,
    const float* __restrict__ Wv, const float* __restrict__ Ws,
    unsigned short* __restrict__ wfrag, int wtotal,
    int* __restrict__ deg, int* __restrict__ cursor, int N) {
    int idx = blockIdx.x * 256 + threadIdx.x;
    if (idx < total4) {
        float4 v = ((const float4*)x)[idx];
        ushort4 o;
        o.x = f2bf(v.x); o.y = f2bf(v.y); o.z = f2bf(v.z); o.w = f2bf(v.w);
        ((ushort4*)xb)[idx] = o;
        return;
    }
    idx -= total4;
    if (idx < wtotal) {
        int j = idx & 7;
        int lane = (idx >> 3) & 63;
        int rest = idx >> 9;
        int chunk = rest & 3;
        int ftile = (rest >> 2) & 7;
        int mat = (rest >> 5) & 3;
        int layer = rest >> 7;
        int k = chunk * 32 + (lane >> 4) * 8 + j;
        int f = ftile * 16 + (lane & 15);
        const float* W = (mat == 0) ? Wq : (mat == 1) ? Wk : (mat == 2) ? Wv : Ws;
        wfrag[idx] = f2bf(W[((size_t)layer * F + k) * F + f]);
        return;
    }
    idx -= wtotal;
    if (idx < N) deg[idx] = 0;
    else if (idx < 2 * N) cursor[idx - N] = 0;
}

// ---------------- CSR build ----------------

__global__ __launch_bounds__(256) void hist_k(const int* __restrict__ dst, int E, int* __restrict__ deg) {
    int e = blockIdx.x * 256 + threadIdx.x;
    if (e < E) atomicAdd(&deg[dst[e]], 1);
}

__global__ __launch_bounds__(256) void scan1_k(const int* __restrict__ deg, int N,
                                               int* __restrict__ start, int* __restrict__ partials) {
    __shared__ int sm[256];
    int t = threadIdx.x;
    int i = blockIdx.x * 256 + t;
    int v = (i < N) ? deg[i] : 0;
    sm[t] = v;
    __syncthreads();
    for (int off = 1; off < 256; off <<= 1) {
        int add = (t >= off) ? sm[t - off] : 0;
        __syncthreads();
        sm[t] += add;
        __syncthreads();
    }
    if (i < N) start[i] = sm[t] - v;
    if (t == 255) partials[blockIdx.x] = sm[t];
}

__global__ __launch_bounds__(256) void scan23_k(const int* __restrict__ partials, int nb,
                                                int* __restrict__ start, int N, int E) {
    __shared__ int sm[256];
    int t = threadIdx.x;
    int v = (t < nb) ? partials[t] : 0;
    sm[t] = v;
    __syncthreads();
    for (int off = 1; off < 256; off <<= 1) {
        int add = (t >= off) ? sm[t - off] : 0;
        __syncthreads();
        sm[t] += add;
        __syncthreads();
    }
    int myoff = sm[t] - v;
    __syncthreads();
    sm[t] = myoff;
    __syncthreads();
    for (int i = t; i < N; i += 256) start[i] += sm[i >> 8];
    if (t == 0) start[N] = E;
}

// epair[i] = (edge_id, src)
__global__ __launch_bounds__(256) void fill_k(const int* __restrict__ src, const int* __restrict__ dst, int E,
                                              const int* __restrict__ start, int* __restrict__ cursor,
                                              int2* __restrict__ epair) {
    int e = blockIdx.x * 256 + threadIdx.x;
    if (e < E) {
        int dd = dst[e];
        int pos = atomicAdd(&cursor[dd], 1);
        epair[start[dd] + pos] = make_int2(e, src[e]);
    }
}

// ---------------- fused QKVS GEMM via bf16 MFMA ----------------
// wave 0:Q 1:K 2:V 3:S, all f16. K and V interleaved: KV[node] = [K row | V row]
// (512B record) so edge_k fetches both with one address base.

__global__ __launch_bounds__(256) void gemm_mfma(
    const unsigned short* __restrict__ xb, const unsigned short* __restrict__ wfrag,
    const float* __restrict__ bq, const float* __restrict__ bk,
    const float* __restrict__ bv, const float* __restrict__ bs,
    unsigned short* __restrict__ Qh, unsigned short* __restrict__ KV,
    unsigned short* __restrict__ Sh, int N) {
    int wave = threadIdx.x >> 6;
    int lane = threadIdx.x & 63;
    int row0 = blockIdx.x * 32;
    int lm = lane & 15, quad = lane >> 4;
    const unsigned short* wf = wfrag + wave * 16384;

    floatx4 acc[2][8];
#pragma unroll
    for (int t = 0; t < 2; t++)
#pragma unroll
        for (int u = 0; u < 8; u++) acc[t][u] = (floatx4){0.f, 0.f, 0.f, 0.f};

#pragma unroll
    for (int chunk = 0; chunk < 4; chunk++) {
        short8 xfr[2];
#pragma unroll
        for (int t = 0; t < 2; t++) {
            int m = row0 + t * 16 + lm;
            m = (m < N) ? m : (N - 1);
            xfr[t] = *(const short8*)(xb + (size_t)m * F + chunk * 32 + quad * 8);
        }
#pragma unroll
        for (int u = 0; u < 8; u++) {
            short8 wfr = *(const short8*)(wf + ((u * 4 + chunk) * 64 + lane) * 8);
            acc[0][u] = __builtin_amdgcn_mfma_f32_16x16x32_bf16(wfr, xfr[0], acc[0][u], 0, 0, 0);
            acc[1][u] = __builtin_amdgcn_mfma_f32_16x16x32_bf16(wfr, xfr[1], acc[1][u], 0, 0, 0);
        }
    }

    const float* bias = (wave == 0) ? bq : (wave == 1) ? bk : (wave == 2) ? bv : bs;
    unsigned short* dp = (wave == 0) ? Qh : (wave == 3) ? Sh : KV;
    int kvwave = (wave == 1 || wave == 2);
    size_t rstride = kvwave ? 256 : 128;
    size_t roff = (wave == 2) ? 128 : 0;
#pragma unroll
    for (int u = 0; u < 8; u++) {
        float4 bv4 = *(const float4*)&bias[u * 16 + quad * 4];
#pragma unroll
        for (int t = 0; t < 2; t++) {
            int node = row0 + t * 16 + lm;
            if (node < N) {
                floatx4 a = acc[t][u];
                size_t off = (size_t)node * rstride + roff + u * 16 + quad * 4;
                *(uint2*)&dp[off] = make_uint2(pkh(a[0] + bv4.x, a[1] + bv4.y),
                                               pkh(a[2] + bv4.z, a[3] + bv4.w));
            }
        }
    }
}

// ---------------- fused edge kernel: single-pass, one wave per destination node ----------------
// Lane (slot=lane>>3, h=lane&7) owns edge set {slot, slot+8, ...} for head h.
// Per edge: ONE 4-load batch (K chunk + V chunk from the interleaved 512B KV
// record), dot -> exp -> w, then immediate V accumulation into 16 f32 regs.
// No second pass, no w/src LDS re-reads. Epilogue: shfl-xor reduce over the 8
// slot-lanes, slots 0-3 write scaled float4 to LDS, all 64 lanes add skip+gelu.

__device__ __forceinline__ float gelu_exact(float v) {
    return 0.5f * v * (1.0f + erff(v * 0.70710678118654752f));
}

__global__ __launch_bounds__(256) void edge_k(
    const unsigned short* __restrict__ Qh, const unsigned short* __restrict__ KV,
    const unsigned short* __restrict__ Sh,
    const int* __restrict__ start, const int2* __restrict__ epair,
    float* __restrict__ aout,
    float* __restrict__ hout_f, unsigned short* __restrict__ hout_b,
    int N, int do_gelu) {
    __shared__ float wbuf[4][64][8];   // w values; tail region reused as output buffer
    __shared__ int sbuf[4][64];        // src byte offsets (src * 512)
    __shared__ int ebuf[4][64];        // edge ids

    int wv = threadIdx.x >> 6;
    int lane = threadIdx.x & 63;
    int n = blockIdx.x * 4 + wv;
    if (n >= N) return;   // no block-level barriers below: safe

    int beg = start[n], end = start[n + 1];
    int deg = end - beg;
    bool multi = deg > 64;
    int slot = lane >> 3, h = lane & 7;

    // q for head h: 16 f16
    const unsigned short* qp = Qh + (size_t)n * F + h * 16;
    uint4 qa = *(const uint4*)(qp);
    uint4 qc = *(const uint4*)(qp + 8);
    half2v q0 = ashalf2(qa.x), q1 = ashalf2(qa.y), q2 = ashalf2(qa.z), q3 = ashalf2(qa.w);
    half2v q4 = ashalf2(qc.x), q5 = ashalf2(qc.y), q6 = ashalf2(qc.z), q7 = ashalf2(qc.w);

    float d = 0.f;
    float b0 = 0.f, b1 = 0.f, b2 = 0.f, b3 = 0.f, b4 = 0.f, b5 = 0.f, b6 = 0.f, b7 = 0.f;
    float b8 = 0.f, b9 = 0.f, b10 = 0.f, b11 = 0.f, b12 = 0.f, b13 = 0.f, b14 = 0.f, b15 = 0.f;

    for (int c0 = beg; c0 < end; c0 += 64) {
        int cnt = min(64, end - c0);

        // one coalesced load covers the chunk; distribute through LDS
        int2 pe = epair[c0 + min(lane, cnt - 1)];
        sbuf[wv][lane] = pe.y << 9;     // src * 256 elems * 2B (KV record)
        ebuf[wv][lane] = pe.x;

        int nit = (cnt + 7) >> 3;
        for (int it = 0; it < nit; it++) {
            int idx = it * 8 + slot;
            bool val = idx < cnt;
            int ofs = sbuf[wv][val ? idx : 0];   // LDS broadcast (8 lanes same addr)
            const unsigned short* kp = (const unsigned short*)((const char*)KV + ofs) + h * 16;
            uint4 ka = *(const uint4*)(kp);          // K features h*16..+7
            uint4 kc = *(const uint4*)(kp + 8);      // K features h*16+8..+15
            uint4 va = *(const uint4*)(kp + 128);    // V features h*16..+7
            uint4 vc = *(const uint4*)(kp + 136);    // V features h*16+8..+15
            float p0 = 0.f, p1 = 0.f;
            p0 = FDOT2(q0, ashalf2(ka.x), p0);
            p0 = FDOT2(q1, ashalf2(ka.y), p0);
            p0 = FDOT2(q2, ashalf2(ka.z), p0);
            p0 = FDOT2(q3, ashalf2(ka.w), p0);
            p1 = FDOT2(q4, ashalf2(kc.x), p1);
            p1 = FDOT2(q5, ashalf2(kc.y), p1);
            p1 = FDOT2(q6, ashalf2(kc.z), p1);
            p1 = FDOT2(q7, ashalf2(kc.w), p1);
            float w = __expf((p0 + p1) * 0.25f);  // 1/sqrt(16)
            if (!val) w = 0.f;
            d += w;
            wbuf[wv][idx][h] = w;
            if (multi && val) aout[(size_t)ebuf[wv][idx] * HEADS + h] = w;  // rare fallback
            // immediate V accumulation (features h*16 .. h*16+15)
            half2v x0 = ashalf2(va.x), x1 = ashalf2(va.y), x2 = ashalf2(va.z), x3 = ashalf2(va.w);
            half2v x4 = ashalf2(vc.x), x5 = ashalf2(vc.y), x6 = ashalf2(vc.z), x7 = ashalf2(vc.w);
            b0  += w * (float)x0[0]; b1  += w * (float)x0[1];
            b2  += w * (float)x1[0]; b3  += w * (float)x1[1];
            b4  += w * (float)x2[0]; b5  += w * (float)x2[1];
            b6  += w * (float)x3[0]; b7  += w * (float)x3[1];
            b8  += w * (float)x4[0]; b9  += w * (float)x4[1];
            b10 += w * (float)x5[0]; b11 += w * (float)x5[1];
            b12 += w * (float)x6[0]; b13 += w * (float)x6[1];
            b14 += w * (float)x7[0]; b15 += w * (float)x7[1];
        }
    }

    // reduce d over slots (lanes sharing h)
    d += __shfl_xor(d, 8);
    d += __shfl_xor(d, 16);
    d += __shfl_xor(d, 32);
    float inv_d = (d > 0.f) ? 1.f / d : 0.f;

    // ---- fused alpha normalization (reads wbuf/ebuf of last=only chunk) ----
    if (!multi) {
        for (int idx = slot; idx < deg; idx += 8)
            aout[(size_t)ebuf[wv][idx] * HEADS + h] = wbuf[wv][idx][h] * inv_d;
    } else {
        for (int idx = slot; idx < deg; idx += 8)
            aout[(size_t)epair[beg + idx].x * HEADS + h] *= inv_d;
    }

    // ---- reduce V accumulators over the 8 slot-lanes of each head ----
    b0  += __shfl_xor(b0, 8);  b0  += __shfl_xor(b0, 16);  b0  += __shfl_xor(b0, 32);
    b1  += __shfl_xor(b1, 8);  b1  += __shfl_xor(b1, 16);  b1  += __shfl_xor(b1, 32);
    b2  += __shfl_xor(b2, 8);  b2  += __shfl_xor(b2, 16);  b2  += __shfl_xor(b2, 32);
    b3  += __shfl_xor(b3, 8);  b3  += __shfl_xor(b3, 16);  b3  += __shfl_xor(b3, 32);
    b4  += __shfl_xor(b4, 8);  b4  += __shfl_xor(b4, 16);  b4  += __shfl_xor(b4, 32);
    b5  += __shfl_xor(b5, 8);  b5  += __shfl_xor(b5, 16);  b5  += __shfl_xor(b5, 32);
    b6  += __shfl_xor(b6, 8);  b6  += __shfl_xor(b6, 16);  b6  += __shfl_xor(b6, 32);
    b7  += __shfl_xor(b7, 8);  b7  += __shfl_xor(b7, 16);  b7  += __shfl_xor(b7, 32);
    b8  += __shfl_xor(b8, 8);  b8  += __shfl_xor(b8, 16);  b8  += __shfl_xor(b8, 32);
    b9  += __shfl_xor(b9, 8);  b9  += __shfl_xor(b9, 16);  b9  += __shfl_xor(b9, 32);
    b10 += __shfl_xor(b10, 8); b10 += __shfl_xor(b10, 16); b10 += __shfl_xor(b10, 32);
    b11 += __shfl_xor(b11, 8); b11 += __shfl_xor(b11, 16); b11 += __shfl_xor(b11, 32);
    b12 += __shfl_xor(b12, 8); b12 += __shfl_xor(b12, 16); b12 += __shfl_xor(b12, 32);
    b13 += __shfl_xor(b13, 8); b13 += __shfl_xor(b13, 16); b13 += __shfl_xor(b13, 32);
    b14 += __shfl_xor(b14, 8); b14 += __shfl_xor(b14, 16); b14 += __shfl_xor(b14, 32);
    b15 += __shfl_xor(b15, 8); b15 += __shfl_xor(b15, 16); b15 += __shfl_xor(b15, 32);

    // ---- write scaled output through LDS (overlays wbuf region) ----
    float* obuf = &wbuf[wv][0][0];   // 128 floats needed, 512 available
    asm volatile("s_waitcnt lgkmcnt(0)" ::: "memory");   // drain norm-loop reads (WAR)
    if (slot == 0) {
        *(float4*)&obuf[h * 16 + 0] = make_float4(b0 * inv_d, b1 * inv_d, b2 * inv_d, b3 * inv_d);
    } else if (slot == 1) {
        *(float4*)&obuf[h * 16 + 4] = make_float4(b4 * inv_d, b5 * inv_d, b6 * inv_d, b7 * inv_d);
    } else if (slot == 2) {
        *(float4*)&obuf[h * 16 + 8] = make_float4(b8 * inv_d, b9 * inv_d, b10 * inv_d, b11 * inv_d);
    } else if (slot == 3) {
        *(float4*)&obuf[h * 16 + 12] = make_float4(b12 * inv_d, b13 * inv_d, b14 * inv_d, b15 * inv_d);
    }
    asm volatile("s_waitcnt lgkmcnt(0)" ::: "memory");

    // each lane owns features f0 = lane*2, f0+1
    int f0 = lane * 2;
    float2 ov = *(const float2*)&obuf[f0];
    half2v s2 = ashalf2(*(const unsigned*)&Sh[(size_t)n * F + f0]);
    float o0 = ov.x + (float)s2[0];
    float o1 = ov.y + (float)s2[1];
    if (do_gelu) {
        o0 = gelu_exact(o0);
        o1 = gelu_exact(o1);
        unsigned ob = (unsigned)f2bf(o0) | ((unsigned)f2bf(o1) << 16);
        *(unsigned*)&hout_b[(size_t)n * F + f0] = ob;
    } else {
        *(float2*)&hout_f[(size_t)n * F + f0] = make_float2(o0, o1);
    }
}

// ---------------- launch ----------------

extern "C" void kernel_launch(void* const* d_in, const int* in_sizes, int n_in,
                              void* d_out, int out_size, void* d_ws, size_t ws_size,
                              hipStream_t stream) {
    const float* x  = (const float*)d_in[0];
    const int*   ei = (const int*)d_in[1];
    const float* Wq = (const float*)d_in[2];
    const float* bq = (const float*)d_in[3];
    const float* Wk = (const float*)d_in[4];
    const float* bk = (const float*)d_in[5];
    const float* Wv = (const float*)d_in[6];
    const float* bv = (const float*)d_in[7];
    const float* Ws = (const float*)d_in[8];
    const float* bs = (const float*)d_in[9];

    const int N = in_sizes[0] / F;
    const int E = in_sizes[1] / 2;
    const int L = in_sizes[2] / (F * F);

    // workspace layout
    unsigned short* Sh = (unsigned short*)d_ws;           // N*F f16
    unsigned short* Qh = Sh + (size_t)N * F;              // N*F f16
    unsigned short* xb = Qh + (size_t)N * F;              // N*F bf16
    unsigned short* hb = xb + (size_t)N * F;              // N*F bf16
    unsigned short* KV = hb + (size_t)N * F;              // N*2F f16 (K|V interleaved)
    unsigned short* wfrag = KV + (size_t)N * 2 * F;       // L*4*16384 bf16
    int2* epair = (int2*)(wfrag + (size_t)L * 4 * 16384); // E int2
    int* start = (int*)(epair + E);                       // N+1
    int* cursor = start + (N + 1);                        // N
    int* deg = cursor + N;                                // N
    int* partials = deg + N;                              // <=256

    float* out_h = (float*)d_out;                         // N*F
    float* out_a = out_h + (size_t)N * F;                 // L*E*HEADS

    const int* srcIdx = ei;
    const int* dstIdx = ei + E;

    int total4 = N * F / 4;
    int wtotal = L * 4 * 16384;
    int stotal = total4 + wtotal + 2 * N;
    setup_k<<<(stotal + 255) / 256, 256, 0, stream>>>(
        x, xb, total4, Wq, Wk, Wv, Ws, wfrag, wtotal, deg, cursor, N);

    int nbScan = (N + 255) / 256;
    hist_k<<<(E + 255) / 256, 256, 0, stream>>>(dstIdx, E, deg);
    scan1_k<<<nbScan, 256, 0, stream>>>(deg, N, start, partials);
    scan23_k<<<1, 256, 0, stream>>>(partials, nbScan, start, N, E);
    fill_k<<<(E + 255) / 256, 256, 0, stream>>>(srcIdx, dstIdx, E, start, cursor, epair);

    for (int l = 0; l < L; ++l) {
        const unsigned short* hin = (l == 0) ? xb : hb;
        gemm_mfma<<<(N + 31) / 32, 256, 0, stream>>>(
            hin, wfrag + (size_t)l * 4 * 16384,
            bq + (size_t)l * F, bk + (size_t)l * F,
            bv + (size_t)l * F, bs + (size_t)l * F,
            Qh, KV, Sh, N);
        edge_k<<<(N + 3) / 4, 256, 0, stream>>>(
            Qh, KV, Sh, start, epair,
            out_a + (size_t)l * E * HEADS, out_h, hb, N, (l < L - 1) ? 1 : 0);
    }
}